// Round 10
// baseline (213.904 us; speedup 1.0000x reference)
//
#include <hip/hip_runtime.h>

// out_f32[t,i,d] = x[t,d]*plm[t,i] + sum_j comb[t,j,i]*res[t,j,d]
// T=8192, HC=4, H=2560. ALL device buffers are f32 (model proven R0-R8;
// R8 passed with absmax 0.03125).
//
// Round-10: round-9 speed version with the compile fix — nontemporal
// builtins need clang ext_vector types, not HIP_vector_type<float,4>.
// 756 MB total @ 6.3 TB/s achievable -> ~120 us floor; predicting ~135-150.

#define HIDDEN 2560
#define HC 4
#define D8 (HIDDEN / 8)   // 320 threads/block, 5 waves

typedef float f32x4 __attribute__((ext_vector_type(4)));

__device__ __forceinline__ f32x4 ntload4(const float* p) {
    return __builtin_nontemporal_load(reinterpret_cast<const f32x4*>(p));
}
__device__ __forceinline__ void ntstore4(float* p, f32x4 v) {
    __builtin_nontemporal_store(v, reinterpret_cast<f32x4*>(p));
}

__global__ __launch_bounds__(D8) void fused_mix_f32(
    const float* __restrict__ x,     // [T, H]
    const float* __restrict__ res,   // [T, HC, H]
    const float* __restrict__ plm,   // [T, HC]
    const float* __restrict__ comb,  // [T, HC, HC]  comb[t][j][i]
    float* __restrict__ out)         // [T, HC, H]
{
    const long t  = blockIdx.x;
    const int  d8 = threadIdx.x;     // 0..319, 8 f32 each

    // Block-uniform coefficients -> scalar (s_load) path.
    const float4 c0 = *reinterpret_cast<const float4*>(comb + t * 16 + 0);   // row j=0
    const float4 c1 = *reinterpret_cast<const float4*>(comb + t * 16 + 4);   // row j=1
    const float4 c2 = *reinterpret_cast<const float4*>(comb + t * 16 + 8);   // row j=2
    const float4 c3 = *reinterpret_cast<const float4*>(comb + t * 16 + 12);  // row j=3
    const float4 p  = *reinterpret_cast<const float4*>(plm  + t * 4);

    const long xoff  = t * HIDDEN + (long)d8 * 8;
    const long rbase = t * (HC * HIDDEN) + (long)d8 * 8;

    // Issue all 10 vector loads up front (independent -> deep in flight).
    const f32x4 xa  = ntload4(x + xoff);
    const f32x4 xb  = ntload4(x + xoff + 4);
    const f32x4 r0a = ntload4(res + rbase + 0 * HIDDEN);
    const f32x4 r0b = ntload4(res + rbase + 0 * HIDDEN + 4);
    const f32x4 r1a = ntload4(res + rbase + 1 * HIDDEN);
    const f32x4 r1b = ntload4(res + rbase + 1 * HIDDEN + 4);
    const f32x4 r2a = ntload4(res + rbase + 2 * HIDDEN);
    const f32x4 r2b = ntload4(res + rbase + 2 * HIDDEN + 4);
    const f32x4 r3a = ntload4(res + rbase + 3 * HIDDEN);
    const f32x4 r3b = ntload4(res + rbase + 3 * HIDDEN + 4);

    // out_i = x*p[i] + c0[i]*r0 + c1[i]*r1 + c2[i]*r2 + c3[i]*r3 (vectorized)
    #define MIX4(XX, R0, R1, R2, R3, PI, C0I, C1I, C2I, C3I)                   \
        (XX * PI + C0I * R0 + C1I * R1 + C2I * R2 + C3I * R3)

    float* op = out + rbase;
    ntstore4(op + 0 * HIDDEN,     MIX4(xa, r0a, r1a, r2a, r3a, p.x, c0.x, c1.x, c2.x, c3.x));
    ntstore4(op + 0 * HIDDEN + 4, MIX4(xb, r0b, r1b, r2b, r3b, p.x, c0.x, c1.x, c2.x, c3.x));
    ntstore4(op + 1 * HIDDEN,     MIX4(xa, r0a, r1a, r2a, r3a, p.y, c0.y, c1.y, c2.y, c3.y));
    ntstore4(op + 1 * HIDDEN + 4, MIX4(xb, r0b, r1b, r2b, r3b, p.y, c0.y, c1.y, c2.y, c3.y));
    ntstore4(op + 2 * HIDDEN,     MIX4(xa, r0a, r1a, r2a, r3a, p.z, c0.z, c1.z, c2.z, c3.z));
    ntstore4(op + 2 * HIDDEN + 4, MIX4(xb, r0b, r1b, r2b, r3b, p.z, c0.z, c1.z, c2.z, c3.z));
    ntstore4(op + 3 * HIDDEN,     MIX4(xa, r0a, r1a, r2a, r3a, p.w, c0.w, c1.w, c2.w, c3.w));
    ntstore4(op + 3 * HIDDEN + 4, MIX4(xb, r0b, r1b, r2b, r3b, p.w, c0.w, c1.w, c2.w, c3.w));
    #undef MIX4
}

extern "C" void kernel_launch(void* const* d_in, const int* in_sizes, int n_in,
                              void* d_out, int out_size, void* d_ws, size_t ws_size,
                              hipStream_t stream) {
    const long T = (long)out_size / ((long)HC * HIDDEN);   // 8192

    // Element-count matching (counts are dtype-independent); positional fallback.
    const long n_x = T * HIDDEN, n_r = T * HC * HIDDEN, n_p = T * HC, n_c = T * HC * HC;
    const float* x = nullptr; const float* res = nullptr;
    const float* plm = nullptr; const float* comb = nullptr;
    for (int i = 0; i < n_in; ++i) {
        const long sz = in_sizes[i];
        if      (sz == n_x) x    = (const float*)d_in[i];
        else if (sz == n_r) res  = (const float*)d_in[i];
        else if (sz == n_p) plm  = (const float*)d_in[i];
        else if (sz == n_c) comb = (const float*)d_in[i];
    }
    if (!x || !res || !plm || !comb) {
        x    = (const float*)d_in[0];
        res  = (const float*)d_in[1];
        plm  = (const float*)d_in[2];
        comb = (const float*)d_in[3];
    }

    fused_mix_f32<<<(int)T, D8, 0, stream>>>(x, res, plm, comb, (float*)d_out);
}

// Round 11
// 147.197 us; speedup vs baseline: 1.4532x; 1.4532x over previous
//
#include <hip/hip_runtime.h>

// out_f32[t,i,d] = x[t,d]*plm[t,i] + sum_j comb[t,j,i]*res[t,j,d]
// T=8192, HC=4, H=2560. ALL device buffers are f32 (proven R0-R8).
//
// Round-11: REVERT nontemporal (R10 post-mortem: nt stores caused 1.6x write
// amplification 336->536 MB + lost L2 write-combining, 183->214 us; nt loads
// forfeited free cross-replay L3 reuse of the static inputs). Keep: no
// sniffer (single dispatch), branchless straight-line float4 math.

#define HIDDEN 2560
#define HC 4
#define D8 (HIDDEN / 8)   // 320 threads/block, 5 waves

__global__ __launch_bounds__(D8) void fused_mix_f32(
    const float* __restrict__ x,     // [T, H]
    const float* __restrict__ res,   // [T, HC, H]
    const float* __restrict__ plm,   // [T, HC]
    const float* __restrict__ comb,  // [T, HC, HC]  comb[t][j][i]
    float* __restrict__ out)         // [T, HC, H]
{
    const long t  = blockIdx.x;
    const int  d8 = threadIdx.x;     // 0..319, 8 f32 each

    // Block-uniform coefficients -> scalar (s_load) path.
    const float4 c0 = *reinterpret_cast<const float4*>(comb + t * 16 + 0);   // row j=0
    const float4 c1 = *reinterpret_cast<const float4*>(comb + t * 16 + 4);   // row j=1
    const float4 c2 = *reinterpret_cast<const float4*>(comb + t * 16 + 8);   // row j=2
    const float4 c3 = *reinterpret_cast<const float4*>(comb + t * 16 + 12);  // row j=3
    const float4 p  = *reinterpret_cast<const float4*>(plm  + t * 4);

    const long xoff  = t * HIDDEN + (long)d8 * 8;
    const long rbase = t * (HC * HIDDEN) + (long)d8 * 8;

    // Issue all 10 vector loads up front (independent -> deep in flight).
    const float4 xa  = *reinterpret_cast<const float4*>(x + xoff);
    const float4 xb  = *reinterpret_cast<const float4*>(x + xoff + 4);
    const float4 r0a = *reinterpret_cast<const float4*>(res + rbase + 0 * HIDDEN);
    const float4 r0b = *reinterpret_cast<const float4*>(res + rbase + 0 * HIDDEN + 4);
    const float4 r1a = *reinterpret_cast<const float4*>(res + rbase + 1 * HIDDEN);
    const float4 r1b = *reinterpret_cast<const float4*>(res + rbase + 1 * HIDDEN + 4);
    const float4 r2a = *reinterpret_cast<const float4*>(res + rbase + 2 * HIDDEN);
    const float4 r2b = *reinterpret_cast<const float4*>(res + rbase + 2 * HIDDEN + 4);
    const float4 r3a = *reinterpret_cast<const float4*>(res + rbase + 3 * HIDDEN);
    const float4 r3b = *reinterpret_cast<const float4*>(res + rbase + 3 * HIDDEN + 4);

    // out_i = x*p[i] + c0[i]*r0 + c1[i]*r1 + c2[i]*r2 + c3[i]*r3
    #define MIX4(XX, R0, R1, R2, R3, PI, C0I, C1I, C2I, C3I)                  \
        make_float4(                                                           \
            XX.x * PI + C0I * R0.x + C1I * R1.x + C2I * R2.x + C3I * R3.x,     \
            XX.y * PI + C0I * R0.y + C1I * R1.y + C2I * R2.y + C3I * R3.y,     \
            XX.z * PI + C0I * R0.z + C1I * R1.z + C2I * R2.z + C3I * R3.z,     \
            XX.w * PI + C0I * R0.w + C1I * R1.w + C2I * R2.w + C3I * R3.w)

    float* op = out + rbase;
    *reinterpret_cast<float4*>(op + 0 * HIDDEN)     = MIX4(xa, r0a, r1a, r2a, r3a, p.x, c0.x, c1.x, c2.x, c3.x);
    *reinterpret_cast<float4*>(op + 0 * HIDDEN + 4) = MIX4(xb, r0b, r1b, r2b, r3b, p.x, c0.x, c1.x, c2.x, c3.x);
    *reinterpret_cast<float4*>(op + 1 * HIDDEN)     = MIX4(xa, r0a, r1a, r2a, r3a, p.y, c0.y, c1.y, c2.y, c3.y);
    *reinterpret_cast<float4*>(op + 1 * HIDDEN + 4) = MIX4(xb, r0b, r1b, r2b, r3b, p.y, c0.y, c1.y, c2.y, c3.y);
    *reinterpret_cast<float4*>(op + 2 * HIDDEN)     = MIX4(xa, r0a, r1a, r2a, r3a, p.z, c0.z, c1.z, c2.z, c3.z);
    *reinterpret_cast<float4*>(op + 2 * HIDDEN + 4) = MIX4(xb, r0b, r1b, r2b, r3b, p.z, c0.z, c1.z, c2.z, c3.z);
    *reinterpret_cast<float4*>(op + 3 * HIDDEN)     = MIX4(xa, r0a, r1a, r2a, r3a, p.w, c0.w, c1.w, c2.w, c3.w);
    *reinterpret_cast<float4*>(op + 3 * HIDDEN + 4) = MIX4(xb, r0b, r1b, r2b, r3b, p.w, c0.w, c1.w, c2.w, c3.w);
    #undef MIX4
}

extern "C" void kernel_launch(void* const* d_in, const int* in_sizes, int n_in,
                              void* d_out, int out_size, void* d_ws, size_t ws_size,
                              hipStream_t stream) {
    const long T = (long)out_size / ((long)HC * HIDDEN);   // 8192

    // Element-count matching (counts are dtype-independent); positional fallback.
    const long n_x = T * HIDDEN, n_r = T * HC * HIDDEN, n_p = T * HC, n_c = T * HC * HC;
    const float* x = nullptr; const float* res = nullptr;
    const float* plm = nullptr; const float* comb = nullptr;
    for (int i = 0; i < n_in; ++i) {
        const long sz = in_sizes[i];
        if      (sz == n_x) x    = (const float*)d_in[i];
        else if (sz == n_r) res  = (const float*)d_in[i];
        else if (sz == n_p) plm  = (const float*)d_in[i];
        else if (sz == n_c) comb = (const float*)d_in[i];
    }
    if (!x || !res || !plm || !comb) {
        x    = (const float*)d_in[0];
        res  = (const float*)d_in[1];
        plm  = (const float*)d_in[2];
        comb = (const float*)d_in[3];
    }

    fused_mix_f32<<<(int)T, D8, 0, stream>>>(x, res, plm, comb, (float*)d_out);
}